// Round 9
// baseline (288.834 us; speedup 1.0000x reference)
//
#include <hip/hip_runtime.h>

typedef __attribute__((ext_vector_type(8))) short bhalf8;
typedef __attribute__((ext_vector_type(4))) short bhalf4;
typedef __attribute__((ext_vector_type(4))) float f32x4;

__device__ __forceinline__ ushort f2bf(float f) {
  unsigned u = __builtin_bit_cast(unsigned, f);
  unsigned r = u + 0x7fffu + ((u >> 16) & 1u);
  return (ushort)(r >> 16);
}

// convert 8 contiguous f32 -> 8 bf16, 16B-vectorized both sides
__device__ __forceinline__ void cvt8(const float* __restrict__ src, ushort* __restrict__ dst) {
  float4 a = *(const float4*)src, b = *(const float4*)(src + 4);
  ushort o[8] = {f2bf(a.x), f2bf(a.y), f2bf(a.z), f2bf(a.w),
                 f2bf(b.x), f2bf(b.y), f2bf(b.z), f2bf(b.w)};
  *(uint4*)dst = *(uint4*)o;
}

// async global->LDS, 16B per lane. Dest = wave-uniform base + lane*16.
__device__ __forceinline__ void gld16(const ushort* g, ushort* l) {
  __builtin_amdgcn_global_load_lds((const __attribute__((address_space(1))) void*)g,
                                   (__attribute__((address_space(3))) void*)l, 16, 0, 0);
}

// 64x64 fp32->bf16 transpose tile via LDS: src row-major (ldsrc), writes
// dst[c][r] = src[r][c]*sc for r,c in [0,64). Coalesced float4 reads,
// contiguous uint4 writes; LDS pad 66 keeps conflicts <=2-way (free).
__device__ __forceinline__ void tile_tr64(const float* __restrict__ src, int ldsrc,
                                          ushort* __restrict__ dst, int lddst,
                                          float sc, ushort* tl, int tid) {
  int r = tid >> 2, cg = (tid & 3) * 16;
  const float* srow = src + (size_t)r * ldsrc + cg;
  float4 a = *(const float4*)srow, b = *(const float4*)(srow + 4),
         c = *(const float4*)(srow + 8), d = *(const float4*)(srow + 12);
  float vals[16] = {a.x, a.y, a.z, a.w, b.x, b.y, b.z, b.w,
                    c.x, c.y, c.z, c.w, d.x, d.y, d.z, d.w};
#pragma unroll
  for (int jj = 0; jj < 16; ++jj) tl[(cg + jj) * 66 + r] = f2bf(vals[jj] * sc);
  __syncthreads();
  int cc = tid >> 2, kg = (tid & 3) * 16;
  uint4 w0 = *(const uint4*)&tl[cc * 66 + kg];
  uint4 w1 = *(const uint4*)&tl[cc * 66 + kg + 8];
  ushort* drow = dst + (size_t)cc * lddst + kg;
  *(uint4*)drow = w0;
  *(uint4*)(drow + 8) = w1;
}

// ---------------- prep: converts, transposes, mask bitpack (inverted), cvec -
// Block-range dispatch. Vectorized converts (8/thr), mask 4/thr with 16-lane
// shfl-OR word assembly, and LDS tile-transposes for e1t/wqkv/wot (the old
// scalar gathers were 32x transaction-amplified). cvec unchanged.
__global__ __launch_bounds__(256) void prep_kernel(
    const float* __restrict__ q, const int* __restrict__ mask,
    const float* __restrict__ eps1, const float* __restrict__ U_w,
    const float* __restrict__ V_w, const float* __restrict__ Wq,
    const float* __restrict__ Wk, const float* __restrict__ Wv,
    const float* __restrict__ Wo, const float* __restrict__ U_b,
    const float* __restrict__ V_b,
    ushort* __restrict__ qb, unsigned long long* __restrict__ minv,
    ushort* __restrict__ uwb, ushort* __restrict__ vwb,
    ushort* __restrict__ e1b, ushort* __restrict__ e1t,
    ushort* __restrict__ wqkv, ushort* __restrict__ wot,
    float* __restrict__ cvec) {
  __shared__ ushort tl[64 * 66];
  int bx = blockIdx.x, tid = threadIdx.x;
  if (bx < 2048) {  // q: 4194304 f32, 8 per thread
    int i = bx * 256 + tid;
    cvt8(q + (size_t)i * 8, qb + (size_t)i * 8);
  } else if (bx < 10240) {  // mask: 8388608 ints, 4 per thread
    int i2 = (bx - 2048) * 256 + tid;
    size_t j0 = (size_t)i2 * 4;  // (b,qq,g) flat, g innermost
    int4 m = *(const int4*)(mask + j0);
    unsigned nib = (m.x == 0 ? 1u : 0u) | (m.y == 0 ? 2u : 0u) |
                   (m.z == 0 ? 4u : 0u) | (m.w == 0 ? 8u : 0u);
    unsigned long long part = (unsigned long long)nib << ((i2 & 15) * 4);
#pragma unroll
    for (int off = 1; off < 16; off <<= 1) part |= __shfl_xor(part, off, 16);
    if ((threadIdx.x & 15) == 0) {
      int b = (int)(j0 >> 20), qq = (int)((j0 >> 10) & 1023), g0 = (int)(j0 & 1023);
      // minv[b][g>>6][q]: bit (g&63) == 1 means KEEP (mask==0)
      minv[((size_t)b * 16 + (g0 >> 6)) * 1024 + qq] = part;
    }
  } else if (bx < 10624) {  // U_w: 786432, 8 per thread
    int j = ((bx - 10240) * 256 + tid) * 8;
    cvt8(U_w + j, uwb + j);
  } else if (bx < 11008) {  // V_w: 786432, 8 per thread
    int j = ((bx - 10624) * 256 + tid) * 8;
    cvt8(V_w + j, vwb + j);
  } else if (bx < 11136) {  // eps1: 262144, 8 per thread
    int j = ((bx - 11008) * 256 + tid) * 8;
    cvt8(eps1 + j, e1b + j);
  } else if (bx < 11200) {  // e1t = eps1^T: 8x8 tiles of 64x64
    int b2 = bx - 11136;
    int r0 = (b2 >> 3) * 64, c0 = (b2 & 7) * 64;
    tile_tr64(eps1 + (size_t)r0 * 512 + c0, 512,
              e1t + (size_t)c0 * 512 + r0, 512, 1.f, tl, tid);
  } else if (bx < 11392) {  // wqkv: per (W, h): transpose [512 d][64 kk] -> [kk][d]
    int b2 = bx - 11200;
    int widx = b2 >> 6, h = (b2 >> 3) & 7, r0 = (b2 & 7) * 64;
    const float* W = (widx == 0) ? Wq : (widx == 1 ? Wk : Wv);
    float sc = (widx == 0) ? 0.02255252509f : 1.0f;  // (1/64)*log2(e) into Wq
    tile_tr64(W + ((size_t)h * 512 + r0) * 64, 64,
              wqkv + ((size_t)widx * 512 + h * 64) * 512 + r0, 512, sc, tl, tid);
  } else if (bx < 11456) {  // wot = Wo^T: 8x8 tiles of 64x64
    int b2 = bx - 11392;
    int r0 = (b2 >> 3) * 64, c0 = (b2 & 7) * 64;
    tile_tr64(Wo + (size_t)r0 * 512 + c0, 512,
              wot + (size_t)c0 * 512 + r0, 512, 1.f, tl, tid);
  } else {  // cvec: blocks [11456, 11840) = 1536 waves
    int j = (bx - 11456) * 256 + tid;
    int idx = j >> 6, ln = j & 63;
    int l = idx >> 9;
    const float* vr = V_w + (size_t)idx * 512 + ln * 8;
    const float* ur = U_b + l * 512 + ln * 8;
    float s = 0;
#pragma unroll
    for (int t = 0; t < 8; t++) s += vr[t] * ur[t];
#pragma unroll
    for (int off = 1; off < 64; off <<= 1) s += __shfl_xor(s, off, 64);
    if (ln == 0) cvec[idx] = s + V_b[idx];
  }
}

// ---------------- bf16 MFMA GEMM, NT, BK=32, dbuf LDS, ONE barrier/step -----
// C[M,N]=A[M,K]*Bt[N,K]^T, tile 128 x BN, 256 thr, grid(x=m-blocks,y=n-blocks)
// (same-x blocks share an XCD -> A L2 reuse). Double-buffered LDS: stage tile
// k+1 into buf^1 right after the barrier, then read frags from buf and MFMA —
// each gld16 gets a full iteration of latency cover and the write-after-read
// hazard spans two barriers (readers of buf^1 finished before this barrier).
// Output region reg=n0>>9 with per-region code: 0=bf16 row-major (+bias if
// bs), 1=fp32 row-major (ptr cast), 2=MFMA-tile scatter
// T[bh][t/16][d/32][t%16][d%32], 3=V^T b128-pair scatter:
// slot = (v>>5)*512 + (v&15)*32 + ((g&15)>>2)*8 + ((v>>4)&1)*4 + (g&3).
template <int BN>
__global__ __launch_bounds__(256) void gemm_nt(
    const ushort* __restrict__ A0, const ushort* __restrict__ A1,
    const ushort* __restrict__ Bt0, const ushort* __restrict__ Bt1,
    int bsplit, int mstride, int M, int K,
    ushort* __restrict__ Oa, const float* __restrict__ ba, int ca,
    ushort* __restrict__ Ob, const float* __restrict__ bb2, int cb,
    ushort* __restrict__ Oc, const float* __restrict__ bc, int cc) {
  __shared__ ushort As[2][128 * 32];
  __shared__ ushort Bs[2][BN * 32];
  int tid = threadIdx.x;
  int wave = tid >> 6, lane = tid & 63;
  int quad = lane >> 4, col = lane & 15;
  int m0 = blockIdx.x * 128, n0 = blockIdx.y * BN;
  const ushort* A = (A1 && n0 >= 512) ? A1 : A0;
  const ushort* Bp = ((n0 < bsplit) ? Bt0 + (size_t)n0 * K
                                    : Bt1 + (size_t)(n0 - bsplit) * K) +
                     (size_t)(m0 >> 9) * mstride;
  constexpr int NI = BN / 32;
  int wm = (BN == 128) ? (wave >> 1) * 64 : (wave & 1) * 64;
  int wn = (BN == 128) ? (wave & 1) * 64 : (wave >> 1) * 32;
  f32x4 acc[4][NI] = {};
  int srow = wave * 16 + (lane >> 2);
  int skc = (lane & 3) * 8;
  const ushort* gA0 = A + (size_t)(m0 + srow) * K + skc;
  const ushort* gA1 = gA0 + (size_t)64 * K;
  const ushort* gB0 = Bp + (size_t)srow * K + skc;
  const ushort* gB1 = gB0 + (size_t)64 * K;
  int lofA0 = wave * 16 * 32;
  int lofA1 = (64 + wave * 16) * 32;

  // stage k-tile 0 into buffer 0
  gld16(gA0, &As[0][lofA0]);
  gld16(gA1, &As[0][lofA1]);
  gld16(gB0, &Bs[0][lofA0]);
  if (BN == 128) gld16(gB1, &Bs[0][lofA1]);

  int cur = 0;
  for (int k0 = 0; k0 < K; k0 += 32) {
    __syncthreads();  // buf[cur] staged (vmcnt drained); buf[cur^1] readers done
    if (k0 + 32 < K) {  // stage next tile into other buffer; full-iter cover
      int nx = cur ^ 1;
      gld16(gA0 + k0 + 32, &As[nx][lofA0]);
      gld16(gA1 + k0 + 32, &As[nx][lofA1]);
      gld16(gB0 + k0 + 32, &Bs[nx][lofA0]);
      if (BN == 128) gld16(gB1 + k0 + 32, &Bs[nx][lofA1]);
    }
    bhalf8 af[4], bg[NI];
#pragma unroll
    for (int i = 0; i < 4; i++)
      af[i] = *(bhalf8*)&As[cur][(wm + i * 16 + col) * 32 + quad * 8];
#pragma unroll
    for (int i = 0; i < NI; i++)
      bg[i] = *(bhalf8*)&Bs[cur][(wn + i * 16 + col) * 32 + quad * 8];
#pragma unroll
    for (int mi = 0; mi < 4; mi++)
#pragma unroll
      for (int ni = 0; ni < NI; ni++)
        acc[mi][ni] = __builtin_amdgcn_mfma_f32_16x16x32_bf16(af[mi], bg[ni], acc[mi][ni], 0, 0, 0);
    cur ^= 1;
  }

  int reg = n0 >> 9;
  ushort* O = (reg == 0) ? Oa : (reg == 1 ? Ob : Oc);
  const float* bs = (reg == 0) ? ba : (reg == 1 ? bb2 : bc);
  int code = (reg == 0) ? ca : (reg == 1 ? cb : cc);
#pragma unroll
  for (int mi = 0; mi < 4; mi++)
#pragma unroll
    for (int ni = 0; ni < NI; ni++) {
      int cn = n0 + wn + ni * 16 + col;
      int cnl = cn & 511;
      int cmb = m0 + wm + mi * 16 + quad * 4;
      float bv = bs ? bs[cnl] : 0.f;
      if (code == 2) {
        int bhh = (cmb >> 10) * 8 + (cnl >> 6);
        size_t base = ((size_t)bhh * 64 + ((cmb & 1023) >> 4)) * 1024 +
                      (size_t)((cnl >> 5) & 1) * 512 + (size_t)(cmb & 15) * 32 + (cnl & 31);
#pragma unroll
        for (int r = 0; r < 4; r++)
          O[base + r * 32] = f2bf(acc[mi][ni][r] + bv);
      } else if (code == 3) {
        int bhh = (cmb >> 10) * 8 + (cnl >> 6);
        int v = cnl & 63;
        size_t base = (size_t)bhh * 65536 + (size_t)((cmb & 1023) >> 4) * 1024 +
                      (size_t)(v >> 5) * 512 + (size_t)(v & 15) * 32 +
                      (size_t)(cmb & 15) * 2 + (size_t)((v >> 4) & 1) * 4;
        ushort4 pk;
        pk.x = f2bf(acc[mi][ni][0] + bv);
        pk.y = f2bf(acc[mi][ni][1] + bv);
        pk.z = f2bf(acc[mi][ni][2] + bv);
        pk.w = f2bf(acc[mi][ni][3] + bv);
        *(ushort4*)&O[base] = pk;
      } else if (code == 1) {
        float* Ff = (float*)O;
#pragma unroll
        for (int r = 0; r < 4; r++)
          Ff[(size_t)(cmb + r) * 512 + cnl] = acc[mi][ni][r] + bv;
      } else {
#pragma unroll
        for (int r = 0; r < 4; r++)
          O[(size_t)(cmb + r) * 512 + cnl] = f2bf(acc[mi][ni][r] + bv);
      }
    }
}

// ---------------- fused LayerNorm + ReLU + residual (z bf16, t bf16) --------
__global__ __launch_bounds__(256) void ln_kernel(
    const ushort* __restrict__ z, const ushort* __restrict__ tb,
    const float* __restrict__ lgam, const float* __restrict__ lbet,
    ushort* __restrict__ hb) {
  int row = blockIdx.x * 4 + (threadIdx.x >> 6);
  int lane = threadIdx.x & 63;
  int cbase = lane * 8;
  uint4 zr = *(const uint4*)&z[(size_t)row * 512 + cbase];
  float x[8];
  {
    const unsigned* u = (const unsigned*)&zr;
#pragma unroll
    for (int w = 0; w < 4; w++) {
      x[2 * w] = __builtin_bit_cast(float, u[w] << 16);
      x[2 * w + 1] = __builtin_bit_cast(float, u[w] & 0xFFFF0000u);
    }
  }
  float sum = 0;
#pragma unroll
  for (int i = 0; i < 8; i++) sum += x[i];
#pragma unroll
  for (int off = 1; off < 64; off <<= 1) sum += __shfl_xor(sum, off, 64);
  float mu = sum * (1.f / 512.f);
  float vs = 0;
#pragma unroll
  for (int i = 0; i < 8; i++) { float d = x[i] - mu; vs += d * d; }
#pragma unroll
  for (int off = 1; off < 64; off <<= 1) vs += __shfl_xor(vs, off, 64);
  float rstd = rsqrtf(vs * (1.f / 512.f) + 1e-5f);
  uint4 tr = *(const uint4*)&tb[(size_t)row * 512 + cbase];
  float tv[8];
  {
    const unsigned* u = (const unsigned*)&tr;
#pragma unroll
    for (int w = 0; w < 4; w++) {
      tv[2 * w] = __builtin_bit_cast(float, u[w] << 16);
      tv[2 * w + 1] = __builtin_bit_cast(float, u[w] & 0xFFFF0000u);
    }
  }
  ushort outv[8];
#pragma unroll
  for (int i = 0; i < 8; i++) {
    float val = (x[i] - mu) * rstd * lgam[cbase + i] + lbet[cbase + i];
    outv[i] = f2bf(tv[i] + fmaxf(val, 0.f));
  }
  *(uint4*)&hb[(size_t)row * 512 + cbase] = *(uint4*)outv;
}

// ---------------- flash attention: LDS-shared K/V, wave-per-qtile -----------
// grid (64 bh, 16 qtile-groups of 4). Block = 4 waves; wave w owns q-tile
// qt=by*4+w and sweeps all 1024 g in 16 groups of 64 g. K/V staged once per
// block into double-buffered LDS via gld16 with ONE barrier per group: stage
// group p+1 into buf^1 right after the barrier (its previous readers finished
// before the barrier), then read frags from buf and compute. All fragment
// reads are ds_read_b128 with 64 lanes tiling contiguous 1024B exactly once
// (zero-conflict). Each V b128 carries TWO v-tiles' A-fragments (split by
// compile-time shuffle). S^T = K*Q^T; exp'd P packs straight into PV
// B-fragments in registers. PV: O^T += V^T*P. No cross-wave reduce.
__global__ __launch_bounds__(256, 4) void attn_kernel(
    const ushort* __restrict__ QtT, const ushort* __restrict__ KtT,
    const ushort* __restrict__ VtT, const unsigned long long* __restrict__ minv,
    ushort* __restrict__ Op) {
  __shared__ ushort lds[16384];  // [2 buf][K 4096 | V 4096] ushorts = 32KB
  int bh = blockIdx.x;
  int b = bh >> 3, h = bh & 7;
  int tid = threadIdx.x, w = tid >> 6, lane = tid & 63;
  int quad = lane >> 4, col = lane & 15;
  int qt = blockIdx.y * 4 + w;
  const ushort* Kg = KtT + (size_t)bh * 65536 + tid * 8;  // per-lane 16B src
  const ushort* Vg = VtT + (size_t)bh * 65536 + tid * 8;
  const ushort* Qt = QtT + (size_t)bh * 65536 + col * 32 + quad * 8;
  bhalf8 bq0 = *(const bhalf8*)(Qt + (size_t)qt * 1024);
  bhalf8 bq1 = *(const bhalf8*)(Qt + (size_t)qt * 1024 + 512);
  f32x4 o[4] = {};  // O^T C-layout: v=vt*16+quad*4+r, q=col
  float lsum = 0.f;
  const unsigned long long* mb = minv + (size_t)b * 16384 + qt * 16 + col;
  int kread = col * 32 + quad * 8;  // ushort offset within a 512-ushort subtile

  {  // stage group 0 into buf 0
    ushort* lk = &lds[w * 512];
    ushort* lv = &lds[4096 + w * 512];
    gld16(Kg, lk); gld16(Kg + 2048, lk + 2048);
    gld16(Vg, lv); gld16(Vg + 2048, lv + 2048);
  }
  unsigned long long mcur = mb[0];

  for (int p = 0; p < 16; ++p) {
    int cb = (p & 1) * 8192;
    __syncthreads();  // buf[cb] staged (vmcnt drained); buf^1 readers done
    unsigned long long mnxt = 0;
    if (p < 15) {  // stage next group into other buffer; full-iter cover
      int nb = cb ^ 8192;
      ushort* lk = &lds[nb + w * 512];
      ushort* lv = &lds[nb + 4096 + w * 512];
      const ushort* gk = Kg + (size_t)(p + 1) * 4096;
      const ushort* gv = Vg + (size_t)(p + 1) * 4096;
      gld16(gk, lk); gld16(gk + 2048, lk + 2048);
      gld16(gv, lv); gld16(gv + 2048, lv + 2048);
      mnxt = mb[(size_t)(p + 1) * 1024];
    }
    bhalf8 ak[4][2];
    bhalf8 avp[4][2];
#pragma unroll
    for (int gt = 0; gt < 4; ++gt) {
      ak[gt][0] = *(const bhalf8*)&lds[cb + gt * 1024 + kread];
      ak[gt][1] = *(const bhalf8*)&lds[cb + gt * 1024 + 512 + kread];
      avp[gt][0] = *(const bhalf8*)&lds[cb + 4096 + gt * 1024 + kread];
      avp[gt][1] = *(const bhalf8*)&lds[cb + 4096 + gt * 1024 + 512 + kread];
    }
#pragma unroll
    for (int gt = 0; gt < 4; ++gt) {
      f32x4 s = {};
      s = __builtin_amdgcn_mfma_f32_16x16x32_bf16(ak[gt][0], bq0, s, 0, 0, 0);
      s = __builtin_amdgcn_mfma_f32_16x16x32_bf16(ak[gt][1], bq1, s, 0, 0, 0);
      unsigned shq = (unsigned)(mcur >> (gt * 16 + quad * 4));
      unsigned pu[4];
#pragma unroll
      for (int r = 0; r < 4; ++r) {
        unsigned keep = (unsigned)((int)(shq << (31 - r)) >> 31);
        pu[r] = __builtin_bit_cast(unsigned, __builtin_amdgcn_exp2f(s[r])) & keep;
        lsum += __builtin_bit_cast(float, pu[r]);
      }
      uint2 pp;
      pp.x = ((pu[0] + 0x8000u) >> 16) | (((pu[1] + 0x8000u) >> 16) << 16);
      pp.y = ((pu[2] + 0x8000u) >> 16) | (((pu[3] + 0x8000u) >> 16) << 16);
      bhalf4 bp = __builtin_bit_cast(bhalf4, pp);
#pragma unroll
      for (int vt = 0; vt < 4; ++vt) {
        bhalf4 av = (vt & 1)
            ? __builtin_shufflevector(avp[gt][vt >> 1], avp[gt][vt >> 1], 4, 5, 6, 7)
            : __builtin_shufflevector(avp[gt][vt >> 1], avp[gt][vt >> 1], 0, 1, 2, 3);
        o[vt] = __builtin_amdgcn_mfma_f32_16x16x16bf16_1k(av, bp, o[vt], 0, 0, 0);
      }
    }
    mcur = mnxt;
  }

  lsum += __shfl_xor(lsum, 16, 64);
  lsum += __shfl_xor(lsum, 32, 64);
  float rl = __builtin_amdgcn_rcpf(lsum);
  int q = qt * 16 + col;
#pragma unroll
  for (int vt = 0; vt < 4; ++vt) {
    ushort4 pk;
    pk.x = f2bf(o[vt][0] * rl);
    pk.y = f2bf(o[vt][1] * rl);
    pk.z = f2bf(o[vt][2] * rl);
    pk.w = f2bf(o[vt][3] * rl);
    *(ushort4*)&Op[(size_t)(b * 1024 + q) * 512 + h * 64 + vt * 16 + quad * 4] = pk;
  }
}

extern "C" void kernel_launch(void* const* d_in, const int* in_sizes, int n_in,
                              void* d_out, int out_size, void* d_ws, size_t ws_size,
                              hipStream_t stream) {
  const float* q    = (const float*)d_in[0];
  const int*   mask = (const int*)d_in[1];
  const float* eps1 = (const float*)d_in[2];
  const float* U_w  = (const float*)d_in[3];
  const float* U_b  = (const float*)d_in[4];
  const float* V_w  = (const float*)d_in[5];
  const float* V_b  = (const float*)d_in[6];
  const float* ln_g = (const float*)d_in[7];
  const float* ln_b = (const float*)d_in[8];
  const float* Wq   = (const float*)d_in[9];
  const float* Wk   = (const float*)d_in[10];
  const float* Wv   = (const float*)d_in[11];
  const float* Wo   = (const float*)d_in[12];
  float* out = (float*)d_out;

  char* ws = (char*)d_ws;
  auto carve = [&](size_t bytes) { char* p = ws; ws += bytes; return p; };
  ushort* qb   = (ushort*)carve(8388608);
  ushort* uwb  = (ushort*)carve(1572864);
  ushort* vwb  = (ushort*)carve(1572864);
  ushort* e1b  = (ushort*)carve(524288);
  ushort* e1t  = (ushort*)carve(524288);
  ushort* wqkv = (ushort*)carve(1572864);
  ushort* wot  = (ushort*)carve(524288);
  ushort* A1b  = (ushort*)carve(1572864);  // A1_l = eps1 @ Uw_l.T
  ushort* Gtb  = (ushort*)carve(1572864);  // Gt_l[n][d]
  float*  cvec = (float*)carve(6144);
  unsigned long long* minv = (unsigned long long*)carve(1048576);
  ushort* tb   = (ushort*)carve(8388608);
  ushort* zb   = (ushort*)carve(8388608);  // z in bf16
  ushort* hb   = (ushort*)carve(8388608);
  ushort* Qtt  = (ushort*)carve(8388608);
  ushort* Ktt  = (ushort*)carve(8388608);
  ushort* Vtt  = (ushort*)carve(8388608);
  ushort* Ob   = (ushort*)carve(8388608);
  const int BIG = 1 << 30;

  prep_kernel<<<11840, 256, 0, stream>>>(q, mask, eps1, U_w, V_w, Wq, Wk, Wv, Wo,
                                         U_b, V_b, qb, minv, uwb, vwb, e1b, e1t,
                                         wqkv, wot, cvec);
  // A1[d, l*512+j] = sum_k eps1[d,k] Uw_l[j,k]
  gemm_nt<128><<<dim3(4, 12), 256, 0, stream>>>(
      e1b, nullptr, uwb, nullptr, BIG, 0, 512, 512,
      A1b, nullptr, 0, A1b + 262144, nullptr, 0, A1b + 524288, nullptr, 0);
  // Gt[l*512+n, d] = sum_j Vw_l[n,j] A1_l[d,j]
  gemm_nt<64><<<dim3(12, 8), 256, 0, stream>>>(
      vwb, nullptr, A1b, nullptr, BIG, 262144, 1536, 512,
      Gtb, nullptr, 0, nullptr, nullptr, 0, nullptr, nullptr, 0);
  const ushort* hsrc = qb;
  for (int l = 0; l < 3; l++) {
    // region0 -> t = h@eps1 (bf16), region1 -> z = h@G_l + c_l (bf16)
    gemm_nt<128><<<dim3(64, 8), 256, 0, stream>>>(
        hsrc, nullptr, e1t, Gtb + l * 262144, 512, 0, 8192, 512,
        tb, nullptr, 0, zb, cvec + l * 512, 0, nullptr, nullptr, 0);
    ln_kernel<<<2048, 256, 0, stream>>>(zb, tb, ln_g + l * 512, ln_b + l * 512, hb);
    hsrc = hb;
  }
  // fused QKV: region0=Q tiled (A=qb), region1=K tiled, region2=V^T tiled (A=hb)
  gemm_nt<128><<<dim3(64, 12), 256, 0, stream>>>(
      qb, hb, wqkv, nullptr, BIG, 0, 8192, 512,
      Qtt, nullptr, 2, Ktt, nullptr, 2, Vtt, nullptr, 3);
  attn_kernel<<<dim3(64, 16), 256, 0, stream>>>(Qtt, Ktt, Vtt, minv, Ob);
  gemm_nt<64><<<dim3(64, 8), 256, 0, stream>>>(
      Ob, nullptr, wot, nullptr, BIG, 0, 8192, 512,
      (ushort*)out, nullptr, 1, nullptr, nullptr, 0, nullptr, nullptr, 0);
}

// Round 10
// 275.081 us; speedup vs baseline: 1.0500x; 1.0500x over previous
//
#include <hip/hip_runtime.h>

typedef __attribute__((ext_vector_type(8))) short bhalf8;
typedef __attribute__((ext_vector_type(4))) short bhalf4;
typedef __attribute__((ext_vector_type(4))) float f32x4;

__device__ __forceinline__ ushort f2bf(float f) {
  unsigned u = __builtin_bit_cast(unsigned, f);
  unsigned r = u + 0x7fffu + ((u >> 16) & 1u);
  return (ushort)(r >> 16);
}

// convert 8 contiguous f32 -> 8 bf16, 16B-vectorized both sides
__device__ __forceinline__ void cvt8(const float* __restrict__ src, ushort* __restrict__ dst) {
  float4 a = *(const float4*)src, b = *(const float4*)(src + 4);
  ushort o[8] = {f2bf(a.x), f2bf(a.y), f2bf(a.z), f2bf(a.w),
                 f2bf(b.x), f2bf(b.y), f2bf(b.z), f2bf(b.w)};
  *(uint4*)dst = *(uint4*)o;
}

// async global->LDS, 16B per lane. Dest = wave-uniform base + lane*16.
__device__ __forceinline__ void gld16(const ushort* g, ushort* l) {
  __builtin_amdgcn_global_load_lds((const __attribute__((address_space(1))) void*)g,
                                   (__attribute__((address_space(3))) void*)l, 16, 0, 0);
}

// 64x64 fp32->bf16 transpose tile via LDS: src row-major (ldsrc), writes
// dst[c][r] = src[r][c]*sc for r,c in [0,64). Coalesced float4 reads,
// contiguous uint4 writes; LDS pad 66 keeps conflicts <=2-way (free).
__device__ __forceinline__ void tile_tr64(const float* __restrict__ src, int ldsrc,
                                          ushort* __restrict__ dst, int lddst,
                                          float sc, ushort* tl, int tid) {
  int r = tid >> 2, cg = (tid & 3) * 16;
  const float* srow = src + (size_t)r * ldsrc + cg;
  float4 a = *(const float4*)srow, b = *(const float4*)(srow + 4),
         c = *(const float4*)(srow + 8), d = *(const float4*)(srow + 12);
  float vals[16] = {a.x, a.y, a.z, a.w, b.x, b.y, b.z, b.w,
                    c.x, c.y, c.z, c.w, d.x, d.y, d.z, d.w};
#pragma unroll
  for (int jj = 0; jj < 16; ++jj) tl[(cg + jj) * 66 + r] = f2bf(vals[jj] * sc);
  __syncthreads();
  int cc = tid >> 2, kg = (tid & 3) * 16;
  uint4 w0 = *(const uint4*)&tl[cc * 66 + kg];
  uint4 w1 = *(const uint4*)&tl[cc * 66 + kg + 8];
  ushort* drow = dst + (size_t)cc * lddst + kg;
  *(uint4*)drow = w0;
  *(uint4*)(drow + 8) = w1;
}

// ---------------- prep: converts, transposes, mask bitpack (inverted), cvec -
// Block-range dispatch. Vectorized converts (8/thr), mask 4/thr with 16-lane
// shfl-OR word assembly, and LDS tile-transposes for e1t/wqkv/wot (the old
// scalar gathers were 32x transaction-amplified). cvec unchanged.
__global__ __launch_bounds__(256) void prep_kernel(
    const float* __restrict__ q, const int* __restrict__ mask,
    const float* __restrict__ eps1, const float* __restrict__ U_w,
    const float* __restrict__ V_w, const float* __restrict__ Wq,
    const float* __restrict__ Wk, const float* __restrict__ Wv,
    const float* __restrict__ Wo, const float* __restrict__ U_b,
    const float* __restrict__ V_b,
    ushort* __restrict__ qb, unsigned long long* __restrict__ minv,
    ushort* __restrict__ uwb, ushort* __restrict__ vwb,
    ushort* __restrict__ e1b, ushort* __restrict__ e1t,
    ushort* __restrict__ wqkv, ushort* __restrict__ wot,
    float* __restrict__ cvec) {
  __shared__ ushort tl[64 * 66];
  int bx = blockIdx.x, tid = threadIdx.x;
  if (bx < 2048) {  // q: 4194304 f32, 8 per thread
    int i = bx * 256 + tid;
    cvt8(q + (size_t)i * 8, qb + (size_t)i * 8);
  } else if (bx < 10240) {  // mask: 8388608 ints, 4 per thread
    int i2 = (bx - 2048) * 256 + tid;
    size_t j0 = (size_t)i2 * 4;  // (b,qq,g) flat, g innermost
    int4 m = *(const int4*)(mask + j0);
    unsigned nib = (m.x == 0 ? 1u : 0u) | (m.y == 0 ? 2u : 0u) |
                   (m.z == 0 ? 4u : 0u) | (m.w == 0 ? 8u : 0u);
    unsigned long long part = (unsigned long long)nib << ((i2 & 15) * 4);
#pragma unroll
    for (int off = 1; off < 16; off <<= 1) part |= __shfl_xor(part, off, 16);
    if ((threadIdx.x & 15) == 0) {
      int b = (int)(j0 >> 20), qq = (int)((j0 >> 10) & 1023), g0 = (int)(j0 & 1023);
      // minv[b][g>>6][q]: bit (g&63) == 1 means KEEP (mask==0)
      minv[((size_t)b * 16 + (g0 >> 6)) * 1024 + qq] = part;
    }
  } else if (bx < 10624) {  // U_w: 786432, 8 per thread
    int j = ((bx - 10240) * 256 + tid) * 8;
    cvt8(U_w + j, uwb + j);
  } else if (bx < 11008) {  // V_w: 786432, 8 per thread
    int j = ((bx - 10624) * 256 + tid) * 8;
    cvt8(V_w + j, vwb + j);
  } else if (bx < 11136) {  // eps1: 262144, 8 per thread
    int j = ((bx - 11008) * 256 + tid) * 8;
    cvt8(eps1 + j, e1b + j);
  } else if (bx < 11200) {  // e1t = eps1^T: 8x8 tiles of 64x64
    int b2 = bx - 11136;
    int r0 = (b2 >> 3) * 64, c0 = (b2 & 7) * 64;
    tile_tr64(eps1 + (size_t)r0 * 512 + c0, 512,
              e1t + (size_t)c0 * 512 + r0, 512, 1.f, tl, tid);
  } else if (bx < 11392) {  // wqkv: per (W, h): transpose [512 d][64 kk] -> [kk][d]
    int b2 = bx - 11200;
    int widx = b2 >> 6, h = (b2 >> 3) & 7, r0 = (b2 & 7) * 64;
    const float* W = (widx == 0) ? Wq : (widx == 1 ? Wk : Wv);
    float sc = (widx == 0) ? 0.02255252509f : 1.0f;  // (1/64)*log2(e) into Wq
    tile_tr64(W + ((size_t)h * 512 + r0) * 64, 64,
              wqkv + ((size_t)widx * 512 + h * 64) * 512 + r0, 512, sc, tl, tid);
  } else if (bx < 11456) {  // wot = Wo^T: 8x8 tiles of 64x64
    int b2 = bx - 11392;
    int r0 = (b2 >> 3) * 64, c0 = (b2 & 7) * 64;
    tile_tr64(Wo + (size_t)r0 * 512 + c0, 512,
              wot + (size_t)c0 * 512 + r0, 512, 1.f, tl, tid);
  } else {  // cvec: blocks [11456, 11840) = 1536 waves
    int j = (bx - 11456) * 256 + tid;
    int idx = j >> 6, ln = j & 63;
    int l = idx >> 9;
    const float* vr = V_w + (size_t)idx * 512 + ln * 8;
    const float* ur = U_b + l * 512 + ln * 8;
    float s = 0;
#pragma unroll
    for (int t = 0; t < 8; t++) s += vr[t] * ur[t];
#pragma unroll
    for (int off = 1; off < 64; off <<= 1) s += __shfl_xor(s, off, 64);
    if (ln == 0) cvec[idx] = s + V_b[idx];
  }
}

// ---------------- bf16 MFMA GEMM, NT, BK=32, pipelined gld16 ----------------
// C[M,N]=A[M,K]*Bt[N,K]^T, tile 128 x BN, 256 thr, grid(x=m-blocks,y=n-blocks)
// (same-x blocks share an XCD -> A L2 reuse; id=x+64y, 64%8==0 keeps
// same-x on one XCD). Single-buffer LDS + 2 barriers/step: at 16KB LDS this
// runs 8 blocks/CU and wave-level TLP hides the barrier drain (the dbuf
// variant halved occupancy and regressed — round 9). Output region
// reg=n0>>9 with per-region code: 0=bf16 row-major (+bias if bs), 1=fp32
// row-major (ptr cast), 2=MFMA-tile scatter T[bh][t/16][d/32][t%16][d%32],
// 3=V^T b128-pair scatter:
// slot = (v>>5)*512 + (v&15)*32 + ((g&15)>>2)*8 + ((v>>4)&1)*4 + (g&3).
template <int BN>
__global__ __launch_bounds__(256) void gemm_nt(
    const ushort* __restrict__ A0, const ushort* __restrict__ A1,
    const ushort* __restrict__ Bt0, const ushort* __restrict__ Bt1,
    int bsplit, int mstride, int M, int K,
    ushort* __restrict__ Oa, const float* __restrict__ ba, int ca,
    ushort* __restrict__ Ob, const float* __restrict__ bb2, int cb,
    ushort* __restrict__ Oc, const float* __restrict__ bc, int cc) {
  __shared__ ushort As[128 * 32];
  __shared__ ushort Bs[BN * 32];
  int tid = threadIdx.x;
  int wave = tid >> 6, lane = tid & 63;
  int quad = lane >> 4, col = lane & 15;
  int m0 = blockIdx.x * 128, n0 = blockIdx.y * BN;
  const ushort* A = (A1 && n0 >= 512) ? A1 : A0;
  const ushort* Bp = ((n0 < bsplit) ? Bt0 + (size_t)n0 * K
                                    : Bt1 + (size_t)(n0 - bsplit) * K) +
                     (size_t)(m0 >> 9) * mstride;
  constexpr int NI = BN / 32;
  int wm = (BN == 128) ? (wave >> 1) * 64 : (wave & 1) * 64;
  int wn = (BN == 128) ? (wave & 1) * 64 : (wave >> 1) * 32;
  f32x4 acc[4][NI] = {};
  int srow = wave * 16 + (lane >> 2);
  int skc = (lane & 3) * 8;
  const ushort* gA0 = A + (size_t)(m0 + srow) * K + skc;
  const ushort* gA1 = gA0 + (size_t)64 * K;
  const ushort* gB0 = Bp + (size_t)srow * K + skc;
  const ushort* gB1 = gB0 + (size_t)64 * K;
  ushort* lA0 = &As[wave * 16 * 32];
  ushort* lA1 = &As[(64 + wave * 16) * 32];
  ushort* lB0 = &Bs[wave * 16 * 32];
  ushort* lB1 = (BN == 128) ? &Bs[(64 + wave * 16) * 32] : nullptr;

  gld16(gA0, lA0);
  gld16(gA1, lA1);
  gld16(gB0, lB0);
  if (BN == 128) gld16(gB1, lB1);

  for (int k0 = 0; k0 < K; k0 += 32) {
    __syncthreads();  // vmcnt drained: tile staged; prev readers done
    bhalf8 af[4], bg[NI];
#pragma unroll
    for (int i = 0; i < 4; i++)
      af[i] = *(bhalf8*)&As[(wm + i * 16 + col) * 32 + quad * 8];
#pragma unroll
    for (int i = 0; i < NI; i++)
      bg[i] = *(bhalf8*)&Bs[(wn + i * 16 + col) * 32 + quad * 8];
    __syncthreads();  // frags in regs; LDS free to overwrite
    if (k0 + 32 < K) {  // stage next tile; DMA overlaps MFMA below
      gld16(gA0 + k0 + 32, lA0);
      gld16(gA1 + k0 + 32, lA1);
      gld16(gB0 + k0 + 32, lB0);
      if (BN == 128) gld16(gB1 + k0 + 32, lB1);
    }
#pragma unroll
    for (int mi = 0; mi < 4; mi++)
#pragma unroll
      for (int ni = 0; ni < NI; ni++)
        acc[mi][ni] = __builtin_amdgcn_mfma_f32_16x16x32_bf16(af[mi], bg[ni], acc[mi][ni], 0, 0, 0);
  }

  int reg = n0 >> 9;
  ushort* O = (reg == 0) ? Oa : (reg == 1 ? Ob : Oc);
  const float* bs = (reg == 0) ? ba : (reg == 1 ? bb2 : bc);
  int code = (reg == 0) ? ca : (reg == 1 ? cb : cc);
#pragma unroll
  for (int mi = 0; mi < 4; mi++)
#pragma unroll
    for (int ni = 0; ni < NI; ni++) {
      int cn = n0 + wn + ni * 16 + col;
      int cnl = cn & 511;
      int cmb = m0 + wm + mi * 16 + quad * 4;
      float bv = bs ? bs[cnl] : 0.f;
      if (code == 2) {
        int bhh = (cmb >> 10) * 8 + (cnl >> 6);
        size_t base = ((size_t)bhh * 64 + ((cmb & 1023) >> 4)) * 1024 +
                      (size_t)((cnl >> 5) & 1) * 512 + (size_t)(cmb & 15) * 32 + (cnl & 31);
#pragma unroll
        for (int r = 0; r < 4; r++)
          O[base + r * 32] = f2bf(acc[mi][ni][r] + bv);
      } else if (code == 3) {
        int bhh = (cmb >> 10) * 8 + (cnl >> 6);
        int v = cnl & 63;
        size_t base = (size_t)bhh * 65536 + (size_t)((cmb & 1023) >> 4) * 1024 +
                      (size_t)(v >> 5) * 512 + (size_t)(v & 15) * 32 +
                      (size_t)(cmb & 15) * 2 + (size_t)((v >> 4) & 1) * 4;
        ushort4 pk;
        pk.x = f2bf(acc[mi][ni][0] + bv);
        pk.y = f2bf(acc[mi][ni][1] + bv);
        pk.z = f2bf(acc[mi][ni][2] + bv);
        pk.w = f2bf(acc[mi][ni][3] + bv);
        *(ushort4*)&O[base] = pk;
      } else if (code == 1) {
        float* Ff = (float*)O;
#pragma unroll
        for (int r = 0; r < 4; r++)
          Ff[(size_t)(cmb + r) * 512 + cnl] = acc[mi][ni][r] + bv;
      } else {
#pragma unroll
        for (int r = 0; r < 4; r++)
          O[(size_t)(cmb + r) * 512 + cnl] = f2bf(acc[mi][ni][r] + bv);
      }
    }
}

// ---------------- fused LayerNorm + ReLU + residual (z bf16, t bf16) --------
__global__ __launch_bounds__(256) void ln_kernel(
    const ushort* __restrict__ z, const ushort* __restrict__ tb,
    const float* __restrict__ lgam, const float* __restrict__ lbet,
    ushort* __restrict__ hb) {
  int row = blockIdx.x * 4 + (threadIdx.x >> 6);
  int lane = threadIdx.x & 63;
  int cbase = lane * 8;
  uint4 zr = *(const uint4*)&z[(size_t)row * 512 + cbase];
  float x[8];
  {
    const unsigned* u = (const unsigned*)&zr;
#pragma unroll
    for (int w = 0; w < 4; w++) {
      x[2 * w] = __builtin_bit_cast(float, u[w] << 16);
      x[2 * w + 1] = __builtin_bit_cast(float, u[w] & 0xFFFF0000u);
    }
  }
  float sum = 0;
#pragma unroll
  for (int i = 0; i < 8; i++) sum += x[i];
#pragma unroll
  for (int off = 1; off < 64; off <<= 1) sum += __shfl_xor(sum, off, 64);
  float mu = sum * (1.f / 512.f);
  float vs = 0;
#pragma unroll
  for (int i = 0; i < 8; i++) { float d = x[i] - mu; vs += d * d; }
#pragma unroll
  for (int off = 1; off < 64; off <<= 1) vs += __shfl_xor(vs, off, 64);
  float rstd = rsqrtf(vs * (1.f / 512.f) + 1e-5f);
  uint4 tr = *(const uint4*)&tb[(size_t)row * 512 + cbase];
  float tv[8];
  {
    const unsigned* u = (const unsigned*)&tr;
#pragma unroll
    for (int w = 0; w < 4; w++) {
      tv[2 * w] = __builtin_bit_cast(float, u[w] << 16);
      tv[2 * w + 1] = __builtin_bit_cast(float, u[w] & 0xFFFF0000u);
    }
  }
  ushort outv[8];
#pragma unroll
  for (int i = 0; i < 8; i++) {
    float val = (x[i] - mu) * rstd * lgam[cbase + i] + lbet[cbase + i];
    outv[i] = f2bf(tv[i] + fmaxf(val, 0.f));
  }
  *(uint4*)&hb[(size_t)row * 512 + cbase] = *(uint4*)outv;
}

// ---------------- flash attention: LDS-shared K/V, wave-per-qtile -----------
// grid (64 bh, 16 qtile-groups of 4). Block = 4 waves; wave w owns q-tile
// qt=by*4+w and sweeps all 1024 g in 16 groups of 64 g. K/V staged once per
// block into double-buffered LDS via gld16 with ONE barrier per group (LDS
// already 2-buffered here so occupancy is unchanged at 4 blocks/CU — unlike
// the gemm where dbuf halved occupancy): stage group p+1 into buf^1 right
// after the barrier (its readers finished before the barrier), then read
// frags from buf and compute under setprio(1) (4 independent blocks/CU give
// the CU scheduler phase diversity to arbitrate). All fragment reads are
// ds_read_b128 with 64 lanes tiling contiguous 1024B exactly once
// (zero-conflict). Each V b128 carries TWO v-tiles' A-fragments (split by
// compile-time shuffle). S^T = K*Q^T; exp'd P packs straight into PV
// B-fragments in registers. PV: O^T += V^T*P. No cross-wave reduce.
__global__ __launch_bounds__(256, 4) void attn_kernel(
    const ushort* __restrict__ QtT, const ushort* __restrict__ KtT,
    const ushort* __restrict__ VtT, const unsigned long long* __restrict__ minv,
    ushort* __restrict__ Op) {
  __shared__ ushort lds[16384];  // [2 buf][K 4096 | V 4096] ushorts = 32KB
  int bh = blockIdx.x;
  int b = bh >> 3, h = bh & 7;
  int tid = threadIdx.x, w = tid >> 6, lane = tid & 63;
  int quad = lane >> 4, col = lane & 15;
  int qt = blockIdx.y * 4 + w;
  const ushort* Kg = KtT + (size_t)bh * 65536 + tid * 8;  // per-lane 16B src
  const ushort* Vg = VtT + (size_t)bh * 65536 + tid * 8;
  const ushort* Qt = QtT + (size_t)bh * 65536 + col * 32 + quad * 8;
  bhalf8 bq0 = *(const bhalf8*)(Qt + (size_t)qt * 1024);
  bhalf8 bq1 = *(const bhalf8*)(Qt + (size_t)qt * 1024 + 512);
  f32x4 o[4] = {};  // O^T C-layout: v=vt*16+quad*4+r, q=col
  float lsum = 0.f;
  const unsigned long long* mb = minv + (size_t)b * 16384 + qt * 16 + col;
  int kread = col * 32 + quad * 8;  // ushort offset within a 512-ushort subtile

  {  // stage group 0 into buf 0
    ushort* lk = &lds[w * 512];
    ushort* lv = &lds[4096 + w * 512];
    gld16(Kg, lk); gld16(Kg + 2048, lk + 2048);
    gld16(Vg, lv); gld16(Vg + 2048, lv + 2048);
  }
  unsigned long long mcur = mb[0];

  for (int p = 0; p < 16; ++p) {
    int cb = (p & 1) * 8192;
    __syncthreads();  // buf[cb] staged (vmcnt drained); buf^1 readers done
    unsigned long long mnxt = 0;
    if (p < 15) {  // stage next group into other buffer; full-iter cover
      int nb = cb ^ 8192;
      ushort* lk = &lds[nb + w * 512];
      ushort* lv = &lds[nb + 4096 + w * 512];
      const ushort* gk = Kg + (size_t)(p + 1) * 4096;
      const ushort* gv = Vg + (size_t)(p + 1) * 4096;
      gld16(gk, lk); gld16(gk + 2048, lk + 2048);
      gld16(gv, lv); gld16(gv + 2048, lv + 2048);
      mnxt = mb[(size_t)(p + 1) * 1024];
    }
    bhalf8 ak[4][2];
    bhalf8 avp[4][2];
#pragma unroll
    for (int gt = 0; gt < 4; ++gt) {
      ak[gt][0] = *(const bhalf8*)&lds[cb + gt * 1024 + kread];
      ak[gt][1] = *(const bhalf8*)&lds[cb + gt * 1024 + 512 + kread];
      avp[gt][0] = *(const bhalf8*)&lds[cb + 4096 + gt * 1024 + kread];
      avp[gt][1] = *(const bhalf8*)&lds[cb + 4096 + gt * 1024 + 512 + kread];
    }
    __builtin_amdgcn_s_setprio(1);
#pragma unroll
    for (int gt = 0; gt < 4; ++gt) {
      f32x4 s = {};
      s = __builtin_amdgcn_mfma_f32_16x16x32_bf16(ak[gt][0], bq0, s, 0, 0, 0);
      s = __builtin_amdgcn_mfma_f32_16x16x32_bf16(ak[gt][1], bq1, s, 0, 0, 0);
      unsigned shq = (unsigned)(mcur >> (gt * 16 + quad * 4));
      unsigned pu[4];
#pragma unroll
      for (int r = 0; r < 4; ++r) {
        unsigned keep = (unsigned)((int)(shq << (31 - r)) >> 31);
        pu[r] = __builtin_bit_cast(unsigned, __builtin_amdgcn_exp2f(s[r])) & keep;
        lsum += __builtin_bit_cast(float, pu[r]);
      }
      uint2 pp;
      pp.x = ((pu[0] + 0x8000u) >> 16) | (((pu[1] + 0x8000u) >> 16) << 16);
      pp.y = ((pu[2] + 0x8000u) >> 16) | (((pu[3] + 0x8000u) >> 16) << 16);
      bhalf4 bp = __builtin_bit_cast(bhalf4, pp);
#pragma unroll
      for (int vt = 0; vt < 4; ++vt) {
        bhalf4 av = (vt & 1)
            ? __builtin_shufflevector(avp[gt][vt >> 1], avp[gt][vt >> 1], 4, 5, 6, 7)
            : __builtin_shufflevector(avp[gt][vt >> 1], avp[gt][vt >> 1], 0, 1, 2, 3);
        o[vt] = __builtin_amdgcn_mfma_f32_16x16x16bf16_1k(av, bp, o[vt], 0, 0, 0);
      }
    }
    __builtin_amdgcn_s_setprio(0);
    mcur = mnxt;
  }

  lsum += __shfl_xor(lsum, 16, 64);
  lsum += __shfl_xor(lsum, 32, 64);
  float rl = __builtin_amdgcn_rcpf(lsum);
  int q = qt * 16 + col;
#pragma unroll
  for (int vt = 0; vt < 4; ++vt) {
    ushort4 pk;
    pk.x = f2bf(o[vt][0] * rl);
    pk.y = f2bf(o[vt][1] * rl);
    pk.z = f2bf(o[vt][2] * rl);
    pk.w = f2bf(o[vt][3] * rl);
    *(ushort4*)&Op[(size_t)(b * 1024 + q) * 512 + h * 64 + vt * 16 + quad * 4] = pk;
  }
}

extern "C" void kernel_launch(void* const* d_in, const int* in_sizes, int n_in,
                              void* d_out, int out_size, void* d_ws, size_t ws_size,
                              hipStream_t stream) {
  const float* q    = (const float*)d_in[0];
  const int*   mask = (const int*)d_in[1];
  const float* eps1 = (const float*)d_in[2];
  const float* U_w  = (const float*)d_in[3];
  const float* U_b  = (const float*)d_in[4];
  const float* V_w  = (const float*)d_in[5];
  const float* V_b  = (const float*)d_in[6];
  const float* ln_g = (const float*)d_in[7];
  const float* ln_b = (const float*)d_in[8];
  const float* Wq   = (const float*)d_in[9];
  const float* Wk   = (const float*)d_in[10];
  const float* Wv   = (const float*)d_in[11];
  const float* Wo   = (const float*)d_in[12];
  float* out = (float*)d_out;

  char* ws = (char*)d_ws;
  auto carve = [&](size_t bytes) { char* p = ws; ws += bytes; return p; };
  ushort* qb   = (ushort*)carve(8388608);
  ushort* uwb  = (ushort*)carve(1572864);
  ushort* vwb  = (ushort*)carve(1572864);
  ushort* e1b  = (ushort*)carve(524288);
  ushort* e1t  = (ushort*)carve(524288);
  ushort* wqkv = (ushort*)carve(1572864);
  ushort* wot  = (ushort*)carve(524288);
  ushort* A1b  = (ushort*)carve(1572864);  // A1_l = eps1 @ Uw_l.T
  ushort* Gtb  = (ushort*)carve(1572864);  // Gt_l[n][d]
  float*  cvec = (float*)carve(6144);
  unsigned long long* minv = (unsigned long long*)carve(1048576);
  ushort* tb   = (ushort*)carve(8388608);
  ushort* zb   = (ushort*)carve(8388608);  // z in bf16
  ushort* hb   = (ushort*)carve(8388608);
  ushort* Qtt  = (ushort*)carve(8388608);
  ushort* Ktt  = (ushort*)carve(8388608);
  ushort* Vtt  = (ushort*)carve(8388608);
  ushort* Ob   = (ushort*)carve(8388608);
  const int BIG = 1 << 30;

  prep_kernel<<<11840, 256, 0, stream>>>(q, mask, eps1, U_w, V_w, Wq, Wk, Wv, Wo,
                                         U_b, V_b, qb, minv, uwb, vwb, e1b, e1t,
                                         wqkv, wot, cvec);
  // A1[d, l*512+j] = sum_k eps1[d,k] Uw_l[j,k]
  gemm_nt<128><<<dim3(4, 12), 256, 0, stream>>>(
      e1b, nullptr, uwb, nullptr, BIG, 0, 512, 512,
      A1b, nullptr, 0, A1b + 262144, nullptr, 0, A1b + 524288, nullptr, 0);
  // Gt[l*512+n, d] = sum_j Vw_l[n,j] A1_l[d,j]
  gemm_nt<64><<<dim3(12, 8), 256, 0, stream>>>(
      vwb, nullptr, A1b, nullptr, BIG, 262144, 1536, 512,
      Gtb, nullptr, 0, nullptr, nullptr, 0, nullptr, nullptr, 0);
  const ushort* hsrc = qb;
  for (int l = 0; l < 3; l++) {
    // region0 -> t = h@eps1 (bf16), region1 -> z = h@G_l + c_l (bf16)
    gemm_nt<128><<<dim3(64, 8), 256, 0, stream>>>(
        hsrc, nullptr, e1t, Gtb + l * 262144, 512, 0, 8192, 512,
        tb, nullptr, 0, zb, cvec + l * 512, 0, nullptr, nullptr, 0);
    ln_kernel<<<2048, 256, 0, stream>>>(zb, tb, ln_g + l * 512, ln_b + l * 512, hb);
    hsrc = hb;
  }
  // fused QKV: region0=Q tiled (A=qb), region1=K tiled, region2=V^T tiled (A=hb)
  gemm_nt<128><<<dim3(64, 12), 256, 0, stream>>>(
      qb, hb, wqkv, nullptr, BIG, 0, 8192, 512,
      Qtt, nullptr, 2, Ktt, nullptr, 2, Vtt, nullptr, 3);
  attn_kernel<<<dim3(64, 16), 256, 0, stream>>>(Qtt, Ktt, Vtt, minv, Ob);
  gemm_nt<64><<<dim3(64, 8), 256, 0, stream>>>(
      Ob, nullptr, wot, nullptr, BIG, 0, 8192, 512,
      (ushort*)out, nullptr, 1, nullptr, nullptr, 0, nullptr, nullptr, 0);
}